// Round 6
// baseline (125.649 us; speedup 1.0000x reference)
//
#include <hip/hip_runtime.h>
#include <stdint.h>

// Round 6: coalesced two-pass speculative scan, 2 waves/SIMD.
// A: elementwise flags+hit/dec (lanes along t, fully coalesced), LDS-transpose
//    of 2-bit flags into [g][tw][r%64] words in d_ws (2 MB).
// B: spec scan SEG=64/W=64 (2x inflation, 2048 single-wave blocks = 8/CU =
//    2 waves/SIMD). Distance-2 load pipeline with named A/B register sets
//    (unroll-2), loads issued at top of each iteration (sched_barrier-pinned),
//    LDS input transpose double-buffered; proj staging aliased onto the
//    inactive buffer half (DS in-order per wave) to fit 18.4KB/block.

#define SEGB 64
#define WB   64
#define CHB  16
#define TILE_T 256
#define SEG4 256
#define W4   128

__device__ __forceinline__ void sdp_step(float e, float srcv, bool active, bool event,
                                         float& c, float& p, float& prj) {
    const float anchor = fmaxf(srcv, 1.0f);
    const float total  = fmaxf(e + c, 0.0f);
    const float f0     = floorf(total + 0.5f);
    const float L = ceilf(anchor - (24.0f + p));   // reference order
    const float U = floorf(anchor + (24.0f - p));
    // verified identity: clamp(max(f0,1),max(L,1),max(U,lower)) == max3(min(f0,U),L,1)
    const float frames = fmaxf(fmaxf(fminf(f0, U), L), 1.0f);
    const float nc = total - frames;
    prj = active ? frames : anchor;
    const float c1 = active ? nc : c;
    c = event ? nc * 0.25f : c1;                    // *0.25 exact
    const float np  = active ? p + (frames - anchor) : p;
    const float npc = fminf(fmaxf(np * 0.25f, -24.0f), 24.0f);
    p = event ? npc : np;
}

// ---------------- Kernel A: flags + hit/dec ----------------
__global__ __launch_bounds__(256)
void sdp_flags_kernel(const float* __restrict__ sp_, const float* __restrict__ co_,
                      const float* __restrict__ bd_, const float* __restrict__ pf_,
                      float* __restrict__ hit_out, float* __restrict__ dec_out,
                      uint32_t* __restrict__ fw, int B, int T) {
    __shared__ uint8_t lb[64][68];            // [row_in_group][t4], +4 pad
    const int ntile = T / TILE_T;
    const int g    = blockIdx.x / ntile;
    const int tile = blockIdx.x % ntile;
    const int tid  = threadIdx.x;
    const int wave = tid >> 6;
    const int l    = tid & 63;

#pragma unroll 4
    for (int i = 0; i < 16; ++i) {
        const int rin = i * 4 + wave;         // wave covers one full row: 1KB contig
        const long long a = (long long)(g * 64 + rin) * T + tile * TILE_T + l * 4;
        const float4 s  = *(const float4*)(sp_ + a);
        const float4 cc = *(const float4*)(co_ + a);
        const float4 b  = *(const float4*)(bd_ + a);
        const float4 f  = *(const float4*)(pf_ + a);
        float4 h;
        uint32_t byte = 0;
#pragma unroll
        for (int k = 0; k < 4; ++k) {
            const bool active = ((&s.x)[k] > 0.5f) || ((&cc.x)[k] > 0.5f);
            const bool event  = active && (((&b.x)[k] >= 0.5f) || ((&f.x)[k] > 0.5f));
            if (active) byte |= 1u << (2 * k);
            if (event)  byte |= 1u << (2 * k + 1);
            (&h.x)[k] = event ? 1.0f : 0.0f;
        }
        *(float4*)(hit_out + a) = h;
        *(float4*)(dec_out + a) = h;          // dec == hit (DECAY<1 static)
        lb[rin][l] = (uint8_t)byte;
    }
    __syncthreads();
    const long long wbase = (long long)g * (T / 16) * 64 +
                            (long long)tile * (TILE_T / 16) * 64;
#pragma unroll
    for (int q = 0; q < 4; ++q) {
        const int idx = q * 256 + tid;
        const int r  = idx & 63;
        const int tw = idx >> 6;
        const uint32_t w = *(const uint32_t*)&lb[r][tw * 4];
        fw[wbase + (long long)tw * 64 + r] = w;
    }
}

// ---------------- Kernel B: coalesced speculative scan ----------------
__global__ __launch_bounds__(64, 2)
void sdp_scan_t_kernel(const float* __restrict__ ex_, const float* __restrict__ src_,
                       const uint32_t* __restrict__ fw,
                       const float* __restrict__ cinit, const float* __restrict__ pinit,
                       float* __restrict__ out, int B, int T, int nseg) {
    __shared__ __align__(16) float exb[2][1152];   // stride-18 rows, double buffer
    __shared__ __align__(16) float srb[2][1152];
    // proj staging aliases exb[buf^1] (DS ops in-order per wave: write->read->
    // stage-overwrite is safe; single-wave block, no cross-wave hazards)

    const int l  = threadIdx.x;
    const int rg = B / 64;
    const int g  = blockIdx.x % rg;
    const int s  = blockIdx.x / rg;

    const int warm = s ? WB : 0;
    const int t0   = s * SEGB - warm;
    const int nch  = (SEGB + warm) / CHB;     // 4 (s==0) or 8 -- even
    const int wch  = warm / CHB;

    const int u0 = l >> 2;
    const int j4 = (l & 3) * 4;
    const long long g64 = (long long)g * 64;
    const long long fwb = (long long)g * (T / 16) * 64;
    const long long BT  = (long long)B * T;

    float c = s ? 0.0f : cinit[g64 + l];
    float p = s ? 0.0f : pinit[g64 + l];

    float4 eA[4], sA[4], eB[4], sB[4];
    uint32_t rfC = 0, rfA = 0, rfB = 0;

    // prologue: chunk0 -> LDS[0] (via B regs), chunk1 -> A regs
    {
        const int tc = t0;
#pragma unroll
        for (int q = 0; q < 4; ++q) {
            const long long a = (g64 + q * 16 + u0) * T + tc + j4;
            eB[q] = *(const float4*)(ex_ + a);
            sB[q] = *(const float4*)(src_ + a);
        }
        rfC = fw[fwb + (long long)(tc >> 4) * 64 + l];
#pragma unroll
        for (int q = 0; q < 4; ++q) {
            const int uu = q * 16 + u0;
            *(float4*)&exb[0][uu * 18 + j4] = eB[q];
            *(float4*)&srb[0][uu * 18 + j4] = sB[q];
        }
    }
    if (nch > 1) {
        const int tc = t0 + CHB;
#pragma unroll
        for (int q = 0; q < 4; ++q) {
            const long long a = (g64 + q * 16 + u0) * T + tc + j4;
            eA[q] = *(const float4*)(ex_ + a);
            sA[q] = *(const float4*)(src_ + a);
        }
        rfA = fw[fwb + (long long)(tc >> 4) * 64 + l];
    }

    int buf = 0;

#define SDP_BODY(CH, eS, sS, rfS, eL, sL, rfL)                                \
    {                                                                         \
        const int ch = (CH);                                                  \
        /* (1) issue loads for chunk ch+2 (distance-2 pipeline) */            \
        if (ch + 2 < nch) {                                                   \
            const int tc = t0 + (ch + 2) * CHB;                               \
            _Pragma("unroll")                                                 \
            for (int q = 0; q < 4; ++q) {                                     \
                const long long a = (g64 + q * 16 + u0) * T + tc + j4;        \
                eL[q] = *(const float4*)(ex_ + a);                            \
                sL[q] = *(const float4*)(src_ + a);                           \
            }                                                                 \
            rfL = fw[fwb + (long long)(tc >> 4) * 64 + l];                    \
        }                                                                     \
        __builtin_amdgcn_sched_barrier(0);                                    \
        /* (2) compute 16 steps from LDS[buf] */                             \
        float4 prj[4];                                                        \
        _Pragma("unroll")                                                     \
        for (int j2 = 0; j2 < 8; ++j2) {                                      \
            const float2 e2 = *(const float2*)&exb[buf][l * 18 + j2 * 2];     \
            const float2 s2 = *(const float2*)&srb[buf][l * 18 + j2 * 2];     \
            _Pragma("unroll")                                                 \
            for (int k = 0; k < 2; ++k) {                                     \
                const int j  = j2 * 2 + k;                                    \
                const int sh = 8 * (j >> 2) + 2 * (j & 3);                    \
                const bool active = (rfC >> sh) & 1u;                         \
                const bool event  = (rfC >> (sh + 1)) & 1u;                   \
                float pr;                                                     \
                sdp_step((&e2.x)[k], (&s2.x)[k], active, event, c, p, pr);    \
                (&prj[j >> 2].x)[j & 3] = pr;                                 \
            }                                                                 \
        }                                                                     \
        /* (3) stores via staging aliased on exb[buf^1] */                    \
        if (ch >= wch) {                                                      \
            float* pjb = &exb[buf ^ 1][0];                                    \
            _Pragma("unroll")                                                 \
            for (int q = 0; q < 4; ++q)                                       \
                *(float4*)&pjb[l * 18 + q * 4] = prj[q];                      \
            const int tc = t0 + ch * CHB;                                     \
            _Pragma("unroll")                                                 \
            for (int q = 0; q < 4; ++q) {                                     \
                const float4 v = *(const float4*)&pjb[(q * 16 + u0) * 18 + j4];\
                *(float4*)(out + (g64 + q * 16 + u0) * T + tc + j4) = v;      \
            }                                                                 \
        }                                                                     \
        __builtin_amdgcn_sched_barrier(0);                                    \
        /* (4) stage chunk ch+1 into the other buffer */                      \
        if (ch + 1 < nch) {                                                   \
            _Pragma("unroll")                                                 \
            for (int q = 0; q < 4; ++q) {                                     \
                const int uu = q * 16 + u0;                                   \
                *(float4*)&exb[buf ^ 1][uu * 18 + j4] = eS[q];                \
                *(float4*)&srb[buf ^ 1][uu * 18 + j4] = sS[q];                \
            }                                                                 \
            rfC = rfS;                                                        \
            buf ^= 1;                                                         \
        }                                                                     \
    }

    for (int ch2 = 0; ch2 + 1 < nch; ch2 += 2) {
        SDP_BODY(ch2,     eA, sA, rfA, eB, sB, rfB);
        SDP_BODY(ch2 + 1, eB, sB, rfB, eA, sA, rfA);
    }
#undef SDP_BODY

    if (s == nseg - 1) {
        out[3 * BT + g64 + l]     = c;
        out[3 * BT + B + g64 + l] = p;
    }
}

// ---------------- fallbacks (round-4 proven) ----------------
__global__ __launch_bounds__(64)
void sdp_spec_kernel(const float* __restrict__ ex_, const float* __restrict__ src_,
                     const float* __restrict__ sp_, const float* __restrict__ co_,
                     const float* __restrict__ bd_, const float* __restrict__ pf_,
                     const float* __restrict__ cinit, const float* __restrict__ pinit,
                     float* __restrict__ out, int B, int T, int nseg) {
    const int lane = threadIdx.x;
    const int rgrps = B / 64;
    const int s = blockIdx.x / rgrps;
    const int r = (blockIdx.x % rgrps) * 64 + lane;
    const long long base = (long long)r * T;
    const long long BT = (long long)B * T;
    const int warm = s ? W4 : 0;
    const int t0 = s * SEG4 - warm;
    const int nch = (SEG4 + warm) / 4;
    const int wch = warm / 4;
    const float* pe  = ex_  + base + t0;
    const float* ps  = src_ + base + t0;
    const float* psp = sp_  + base + t0;
    const float* pco = co_  + base + t0;
    const float* pbd = bd_  + base + t0;
    const float* ppf = pf_  + base + t0;
    float* pproj = out + base + t0;
    float* phit  = out + BT + base + t0;
    float* pdec  = out + 2 * BT + base + t0;
    float c = s ? 0.0f : cinit[r];
    float p = s ? 0.0f : pinit[r];
    float4 e4 = *(const float4*)(pe), s4 = *(const float4*)(ps);
    float4 sp4 = *(const float4*)(psp), co4 = *(const float4*)(pco);
    float4 bd4 = *(const float4*)(pbd), pf4 = *(const float4*)(ppf);
    for (int ch = 0; ch < nch; ++ch) {
        float4 ne, ns, nsp, nco, nbd, npf;
        const bool more = (ch + 1 < nch);
        if (more) {
            const int tn = (ch + 1) * 4;
            ne = *(const float4*)(pe + tn);  ns = *(const float4*)(ps + tn);
            nsp = *(const float4*)(psp + tn); nco = *(const float4*)(pco + tn);
            nbd = *(const float4*)(pbd + tn); npf = *(const float4*)(ppf + tn);
        }
        float4 prj, ht;
#pragma unroll
        for (int k = 0; k < 4; ++k) {
            const bool active = ((&sp4.x)[k] > 0.5f) || ((&co4.x)[k] > 0.5f);
            const bool event  = active && (((&bd4.x)[k] >= 0.5f) || ((&pf4.x)[k] > 0.5f));
            float pr;
            sdp_step((&e4.x)[k], (&s4.x)[k], active, event, c, p, pr);
            (&prj.x)[k] = pr;
            (&ht.x)[k]  = event ? 1.0f : 0.0f;
        }
        if (ch >= wch) {
            const int t = ch * 4;
            *(float4*)(pproj + t) = prj;
            *(float4*)(phit  + t) = ht;
            *(float4*)(pdec  + t) = ht;
        }
        if (more) { e4 = ne; s4 = ns; sp4 = nsp; co4 = nco; bd4 = nbd; pf4 = npf; }
    }
    if (s == nseg - 1) {
        out[3 * BT + r]     = c;
        out[3 * BT + B + r] = p;
    }
}

__global__ __launch_bounds__(64)
void sdp_simple_kernel(const float* __restrict__ ex_, const float* __restrict__ src_,
                       const float* __restrict__ sp_, const float* __restrict__ co_,
                       const float* __restrict__ bd_, const float* __restrict__ pf_,
                       const float* __restrict__ cinit, const float* __restrict__ pinit,
                       float* __restrict__ out, int B, int T) {
    const int r = blockIdx.x * 64 + threadIdx.x;
    if (r >= B) return;
    const long long base = (long long)r * T;
    const long long BT = (long long)B * T;
    float c = cinit[r];
    float p = pinit[r];
    for (int t = 0; t < T; ++t) {
        const bool active = (sp_[base + t] > 0.5f) || (co_[base + t] > 0.5f);
        const bool event  = active && ((bd_[base + t] >= 0.5f) || (pf_[base + t] > 0.5f));
        float pr;
        sdp_step(ex_[base + t], src_[base + t], active, event, c, p, pr);
        out[base + t] = pr;
        const float h = event ? 1.0f : 0.0f;
        out[BT + base + t] = h;
        out[2 * BT + base + t] = h;
    }
    out[3 * BT + r]     = c;
    out[3 * BT + B + r] = p;
}

extern "C" void kernel_launch(void* const* d_in, const int* in_sizes, int n_in,
                              void* d_out, int out_size, void* d_ws, size_t ws_size,
                              hipStream_t stream) {
    const float* ex_  = (const float*)d_in[0];
    const float* src_ = (const float*)d_in[1];
    const float* sp_  = (const float*)d_in[2];
    const float* co_  = (const float*)d_in[3];
    const float* bd_  = (const float*)d_in[4];
    const float* pf_  = (const float*)d_in[5];
    const float* ci_  = (const float*)d_in[6];
    const float* pi_  = (const float*)d_in[7];

    const int B = in_sizes[6];
    const int T = in_sizes[0] / B;
    float* out = (float*)d_out;
    const long long BT = (long long)B * T;
    const size_t need_ws = (size_t)B * (size_t)(T / 16) * 4;

    if ((B % 64) == 0 && (T % TILE_T) == 0 && (T % SEGB) == 0 && T >= 2 * SEGB &&
        ws_size >= need_ws) {
        uint32_t* fw = (uint32_t*)d_ws;
        const int ablocks = (B / 64) * (T / TILE_T);
        sdp_flags_kernel<<<dim3(ablocks), dim3(256), 0, stream>>>(
            sp_, co_, bd_, pf_, out + BT, out + 2 * BT, fw, B, T);
        const int nseg = T / SEGB;
        const int bblocks = nseg * (B / 64);
        sdp_scan_t_kernel<<<dim3(bblocks), dim3(64), 0, stream>>>(
            ex_, src_, fw, ci_, pi_, out, B, T, nseg);
    } else if ((B % 64) == 0 && (T % SEG4) == 0 && T >= SEG4 + W4) {
        const int nseg = T / SEG4;
        sdp_spec_kernel<<<dim3((B / 64) * nseg), dim3(64), 0, stream>>>(
            ex_, src_, sp_, co_, bd_, pf_, ci_, pi_, out, B, T, nseg);
    } else {
        sdp_simple_kernel<<<dim3((B + 63) / 64), dim3(64), 0, stream>>>(
            ex_, src_, sp_, co_, bd_, pf_, ci_, pi_, out, B, T);
    }
}